// Round 8
// baseline (172.262 us; speedup 1.0000x reference)
//
#include <hip/hip_runtime.h>

// ---------------------------------------------------------------------------
// QuaternionLinear == one dense GEMM: out[M,N] = x[M,K] @ W_eff[N,K]^T + bias
//   M = 16384 (B*S), N = 2048 (OUT_F), K = 2048 (IN_F)
// Pipeline: prep (fp32->bf16 x + build W_eff) ; qgemm.
// R8: occupancy attack. 256x256 tile, BK=64, **16 waves (4x4), 1024 thr,
// per-wave 64x64** -> acc 64 regs, total <=128/wave, 4 waves/SIMD (vs 2).
// R5-R7 showed MfmaUtil pinned at ~50% for ANY sync structure at 2 waves/
// SIMD (aligned MFMA clusters leave the matrix pipe idle during read
// phases); more waves/SIMD is the only remaining lever for overlap.
// Kept from R7: A 2-ring + B 3-ring LDS (160KB), chunk-XOR swizzle (T2),
// single end-of-tile sync w/ counted vmcnt (T3/T4), literal ring indices
// (6-tile unroll), XCD swizzle (T1), fused prep.
// ---------------------------------------------------------------------------

typedef unsigned short u16;
typedef __bf16 bf16x8 __attribute__((ext_vector_type(8)));
typedef float f32x4 __attribute__((ext_vector_type(4)));

#define QM 16384
#define QN 2048
#define QK 2048

__device__ __forceinline__ u16 f2bf(float f) {
    union { float f; unsigned u; } v;
    v.f = f;
    unsigned r = v.u + 0x7FFFu + ((v.u >> 16) & 1u);
    return (u16)(r >> 16);
}

__device__ __forceinline__ void async_copy16(const u16* g, u16* l) {
    __builtin_amdgcn_global_load_lds(
        (const __attribute__((address_space(1))) void*)g,
        (__attribute__((address_space(3))) void*)l,
        16, 0, 0);
}

// ---------------------------------------------------------------------------
// prep: blocks [0,4096) convert x fp32->bf16; blocks [4096,8192) build W_eff.
// ---------------------------------------------------------------------------
__global__ void prep_kernel(const float* __restrict__ x, u16* __restrict__ xb,
                            const float* __restrict__ wr, const float* __restrict__ wi,
                            const float* __restrict__ wj, const float* __restrict__ wk,
                            u16* __restrict__ wb) {
    const int b = blockIdx.x;
    if (b < 4096) {
        const int n4 = (QM * QK) / 4;
        for (int i = b * blockDim.x + threadIdx.x; i < n4; i += 4096 * blockDim.x) {
            float4 v = reinterpret_cast<const float4*>(x)[i];
            ushort4 o;
            o.x = f2bf(v.x); o.y = f2bf(v.y); o.z = f2bf(v.z); o.w = f2bf(v.w);
            reinterpret_cast<ushort4*>(xb)[i] = o;
        }
    } else {
        int i = (b - 4096) * blockDim.x + threadIdx.x;   // [0, QN*QK/4)
        int n = i >> 9;
        int p = i & 511;
        int q = n >> 2, co = n & 3;
        int base = (q << 9) + p;
        float r  = wr[base], ii = wi[base], jj = wj[base], kk = wk[base];
        float e0, e1, e2, e3;
        if      (co == 0) { e0 = r;  e1 = -ii; e2 = -jj; e3 = -kk; }
        else if (co == 1) { e0 = ii; e1 = r;   e2 = -jj; e3 = kk;  }
        else if (co == 2) { e0 = jj; e1 = ii;  e2 = r;   e3 = -kk; }
        else              { e0 = kk; e1 = -ii; e2 = jj;  e3 = r;   }
        ushort4 o;
        o.x = f2bf(e0); o.y = f2bf(e1); o.z = f2bf(e2); o.w = f2bf(e3);
        reinterpret_cast<ushort4*>(wb)[(n << 9) + p] = o;
    }
}

// ---------------------------------------------------------------------------
// LDS (u16): A bufs [0,32768) = 2 x 16384; B bufs [32768,81920) = 3 x 16384.
// Buf = 256 rows x 64 cols; physical 16B-chunk (r,cp) holds logical
// (r, cp ^ (r&7)) [involution, both-sides swizzle].
// Per K-tile t: read A-buf t&1, B-buf t%3; stage A(t+1) (2 half-loads, in
// ks0 cluster) and B(t+2) (2 half-loads, in ks1 cluster).
// One end-of-tile sync: lgkm(0)+vmcnt(2)+barrier.
// Race-safety (same proof as R6/R7):
//   [1] A(t+1) dest buf^1: tile-(t-1) readers drained at t-1's end sync;
//       residency for t+1 via end vmcnt(2).
//   [2] B(t+2) dest (t+2)%3 disjoint from read buf t%3 and (t+1)%3;
//       buf t%3 next written at tile t+1 (B(t+3)), after my reads drained.
//   [3] end-of-tile in-flight queue = [B(t+1)x2, A(t+1)x2, B(t+2)x2];
//       vmcnt(2) => tile t+1 fully resident, B(t+2) stays in flight.
// Staging with 1024 threads: half-tile (128x64) = 1024 chunks of 16B = one
// chunk/thread -> ONE async_copy16 per stage call; wave w covers rows
// [w*8,(w+1)*8) -> LDS dest = lbase + wid*512 (wave-uniform + lane*16). 
// ---------------------------------------------------------------------------
__global__ __launch_bounds__(1024, 4) void qgemm_kernel(const u16* __restrict__ A,
                                                        const u16* __restrict__ B,
                                                        const float* __restrict__ bias,
                                                        float* __restrict__ C) {
    __shared__ __align__(16) u16 L[81920];      // 160 KB

    const int bid = blockIdx.x;                 // 512 blocks, %8==0
    const int swz = (bid & 7) * 64 + (bid >> 3);
    const int bm = swz >> 3;                    // 0..63
    const int bn = swz & 7;                     // 0..7

    const int tid = threadIdx.x;
    const int wid = tid >> 6, lane = tid & 63;
    const int wm = wid >> 2, wn = wid & 3;      // 4x4 wave grid
    const int lr = lane & 15, lg = lane >> 4;

    const u16* Asrc = A + (size_t)bm * 256 * QK;
    const u16* Bsrc = B + (size_t)bn * 256 * QK;

    // staging: thread covers chunk tid of a 128x64 half-tile
    const int rA  = tid >> 3;                        // 0..127
    const int clA = ((tid & 7) ^ (rA & 7)) << 3;     // pre-swizzled global col
    const size_t soff = (size_t)rA * QK + clA;

    f32x4 acc[4][4];
#pragma unroll
    for (int i = 0; i < 4; ++i)
#pragma unroll
        for (int j = 0; j < 4; ++j)
            acc[i][j] = (f32x4){0.f, 0.f, 0.f, 0.f};

    auto stage = [&](const u16* src, int lbase, int k0) {
        async_copy16(src + k0 + soff, &L[lbase + wid * 512]);
    };

    auto rdA = [&](const u16* LA, int mf, int ks) -> bf16x8 {
        const int r = wm * 64 + mf * 16 + lr;
        const int c = ((ks * 4 + lg) ^ (r & 7)) << 3;
        return *(const bf16x8*)&LA[r * 64 + c];
    };
    auto rdB = [&](const u16* LB, int nf, int ks) -> bf16x8 {
        const int r = wn * 64 + nf * 16 + lr;
        const int c = ((ks * 4 + lg) ^ (r & 7)) << 3;
        return *(const bf16x8*)&LB[r * 64 + c];
    };

    // ab, bt, bt2 are LITERAL constants at every call site (address CSE).
    auto doTile = [&](const int ab, const int bt, const int bt2, const int t)
        __attribute__((always_inline)) {
        const u16* LA = &L[ab * 16384];
        const u16* LB = &L[32768 + bt * 16384];
        const int tw1 = (t + 1) & 31, tw2 = (t + 2) & 31;
        const int oA = (ab ^ 1) * 16384;          // A dest buf
        const int oB = 32768 + bt2 * 16384;       // B dest buf

        // ---- cluster ks0: 8 reads, stage A(t+1) both halves, 16 MFMA ----
        {
            bf16x8 a[4], b[4];
#pragma unroll
            for (int nf = 0; nf < 4; ++nf) b[nf] = rdB(LB, nf, 0);
#pragma unroll
            for (int mf = 0; mf < 4; ++mf) a[mf] = rdA(LA, mf, 0);
            stage(Asrc,            oA,        tw1 * 64);
            stage(Asrc + 128 * QK, oA + 8192, tw1 * 64);
#pragma unroll
            for (int mf = 0; mf < 4; ++mf)
#pragma unroll
                for (int nf = 0; nf < 4; ++nf)
                    acc[mf][nf] = __builtin_amdgcn_mfma_f32_16x16x32_bf16(a[mf], b[nf], acc[mf][nf], 0, 0, 0);
        }

        // ---- cluster ks1: 8 reads, stage B(t+2) both halves, 16 MFMA ----
        {
            bf16x8 a[4], b[4];
#pragma unroll
            for (int nf = 0; nf < 4; ++nf) b[nf] = rdB(LB, nf, 1);
#pragma unroll
            for (int mf = 0; mf < 4; ++mf) a[mf] = rdA(LA, mf, 1);
            stage(Bsrc,            oB,        tw2 * 64);
            stage(Bsrc + 128 * QK, oB + 8192, tw2 * 64);
#pragma unroll
            for (int mf = 0; mf < 4; ++mf)
#pragma unroll
                for (int nf = 0; nf < 4; ++nf)
                    acc[mf][nf] = __builtin_amdgcn_mfma_f32_16x16x32_bf16(a[mf], b[nf], acc[mf][nf], 0, 0, 0);
        }

        // single sync point: tile t+1 resident, all my LDS reads drained
        asm volatile("s_waitcnt lgkmcnt(0) vmcnt(2)" ::: "memory");
        __builtin_amdgcn_s_barrier();
    };

    // prologue: A(0)->Abuf0, B(0)->Bbuf0, B(1)->Bbuf1
    stage(Asrc,            0,             0);
    stage(Asrc + 128 * QK, 8192,          0);
    stage(Bsrc,            32768,             0);
    stage(Bsrc + 128 * QK, 32768 + 8192,      0);
    stage(Bsrc,            32768 + 16384,        64);
    stage(Bsrc + 128 * QK, 32768 + 16384 + 8192, 64);
    asm volatile("s_waitcnt vmcnt(2)" ::: "memory");   // A(0),B(0) resident
    __builtin_amdgcn_s_barrier();

    // 32 tiles = 5 x 6 (lcm of rings 2,3) + 2 tail; literal ring indices.
    for (int t = 0; t < 30; t += 6) {
        doTile(0, 0, 2, t);
        doTile(1, 1, 0, t + 1);
        doTile(0, 2, 1, t + 2);
        doTile(1, 0, 2, t + 3);
        doTile(0, 1, 0, t + 4);
        doTile(1, 2, 1, t + 5);
    }
    doTile(0, 0, 2, 30);
    doTile(1, 1, 0, 31);

    // epilogue: C/D layout col = lane&15, row = (lane>>4)*4 + reg
    const int colbase = bn * 256 + wn * 64;
    const int rowbase = bm * 256 + wm * 64;
    float bsv[4];
#pragma unroll
    for (int nf = 0; nf < 4; ++nf) bsv[nf] = bias[colbase + nf * 16 + lr];
    float* Cb = C + (size_t)rowbase * QN + colbase;
#pragma unroll
    for (int mf = 0; mf < 4; ++mf)
#pragma unroll
        for (int nf = 0; nf < 4; ++nf)
#pragma unroll
            for (int v = 0; v < 4; ++v)
                Cb[(size_t)(mf * 16 + lg * 4 + v) * QN + nf * 16 + lr] = acc[mf][nf][v] + bsv[nf];
}

// ---------------------------------------------------------------------------
extern "C" void kernel_launch(void* const* d_in, const int* in_sizes, int n_in,
                              void* d_out, int out_size, void* d_ws, size_t ws_size,
                              hipStream_t stream) {
    const float* x    = (const float*)d_in[0];
    const float* wr   = (const float*)d_in[1];
    const float* wi   = (const float*)d_in[2];
    const float* wj   = (const float*)d_in[3];
    const float* wk   = (const float*)d_in[4];
    const float* bias = (const float*)d_in[5];
    float* out = (float*)d_out;

    u16* xb = (u16*)d_ws;                                   // 64 MB
    u16* wb = (u16*)((char*)d_ws + (size_t)QM * QK * 2);    // 8 MB

    prep_kernel<<<8192, 256, 0, stream>>>(x, xb, wr, wi, wj, wk, wb);
    qgemm_kernel<<<512, 1024, 0, stream>>>(xb, wb, bias, out);
}